// Round 1
// baseline (329.644 us; speedup 1.0000x reference)
//
#include <hip/hip_runtime.h>

// GatingLayer: logits = x[16384,3072] . W[8,3072]^T + b[8]; softmax(8);
// top-2 (lowest-index tie-break); softmax over the 2 selected scores.
// Outputs concatenated in d_out: values (fp32 x 32768) then indices
// (written as float x 32768, harness reads whole buffer as fp32).

#define NTOK   16384
#define DMODEL 3072
#define NEXP   8
#define NDB    16                 // d-split across blockIdx.y
#define DCH    (DMODEL / NDB)     // 192 d per block
#define DS     32                 // d per LDS sub-chunk
#define NSUB   (DCH / DS)         // 6
#define TPB    256                // threads per block == tokens per block

// Phase 1: partial logits via LDS-staged x, wave-uniform scalar W reads,
// fp32 atomicAdd combine across the 16 d-chunks.
__global__ __launch_bounds__(TPB) void gate_logits_kernel(
    const float* __restrict__ x, const float* __restrict__ W,
    float* __restrict__ logits) {
  // +1 pad -> stride 33 floats: b32 reads xt[tid][j] hit banks (tid+j)%32,
  // 2 lanes/bank for wave64 = free (m136).
  __shared__ float xt[TPB][DS + 1];

  const int tid = threadIdx.x;
  const int tokBase = blockIdx.x * TPB;
  const int dBase = blockIdx.y * DCH;

  float acc[NEXP];
#pragma unroll
  for (int e = 0; e < NEXP; ++e) acc[e] = 0.f;

  for (int s = 0; s < NSUB; ++s) {
    const int dc = dBase + s * DS;
    // Stage 256 tokens x 32 d: 2048 float4 loads, 8 per thread, coalesced
    // (8 consecutive lanes cover one token's 128 B row segment).
#pragma unroll
    for (int i = 0; i < 8; ++i) {
      const int f = i * TPB + tid;        // [0, 2048)
      const int tok = f >> 3;             // [0, 256)
      const int d4 = (f & 7) << 2;        // {0,4,...,28}
      const float4 v =
          *(const float4*)&x[(size_t)(tokBase + tok) * DMODEL + dc + d4];
      xt[tok][d4 + 0] = v.x;
      xt[tok][d4 + 1] = v.y;
      xt[tok][d4 + 2] = v.z;
      xt[tok][d4 + 3] = v.w;
    }
    __syncthreads();

    // thread == token; W index is wave-uniform -> scalar loads.
#pragma unroll
    for (int j = 0; j < DS; ++j) {
      const float xv = xt[tid][j];
#pragma unroll
      for (int e = 0; e < NEXP; ++e) {
        acc[e] = fmaf(xv, W[e * DMODEL + dc + j], acc[e]);
      }
    }
    __syncthreads();
  }

#pragma unroll
  for (int e = 0; e < NEXP; ++e) {
    atomicAdd(&logits[(size_t)(tokBase + tid) * NEXP + e], acc[e]);
  }
}

// Phase 2: bias + softmax(8) + top-2 + renorm softmax(2). One thread/token.
__global__ __launch_bounds__(256) void gate_topk_kernel(
    const float* __restrict__ logits, const float* __restrict__ bias,
    float* __restrict__ out) {
  const int t = blockIdx.x * blockDim.x + threadIdx.x;
  if (t >= NTOK) return;

  float l[NEXP];
#pragma unroll
  for (int e = 0; e < NEXP; ++e) l[e] = logits[(size_t)t * NEXP + e] + bias[e];

  float m = l[0];
#pragma unroll
  for (int e = 1; e < NEXP; ++e) m = fmaxf(m, l[e]);

  float p[NEXP];
  float ssum = 0.f;
#pragma unroll
  for (int e = 0; e < NEXP; ++e) {
    p[e] = expf(l[e] - m);
    ssum += p[e];
  }
  const float inv = 1.f / ssum;
#pragma unroll
  for (int e = 0; e < NEXP; ++e) p[e] *= inv;

  // top-2 on gate scores, first-occurrence (lowest index) on ties,
  // matching jax.lax.top_k's stable ordering.
  int i1 = 0;
  float v1 = p[0];
#pragma unroll
  for (int e = 1; e < NEXP; ++e) {
    if (p[e] > v1) { v1 = p[e]; i1 = e; }
  }
  int i2 = -1;
  float v2 = -1.f;
#pragma unroll
  for (int e = 0; e < NEXP; ++e) {
    if (e == i1) continue;
    if (p[e] > v2) { v2 = p[e]; i2 = e; }
  }

  // softmax([v1, v2]) with v1 >= v2: [1, e2] / (1 + e2), e2 = exp(v2-v1).
  const float e2 = expf(v2 - v1);
  const float r = 1.f / (1.f + e2);

  out[(size_t)t * 2 + 0] = r;
  out[(size_t)t * 2 + 1] = e2 * r;
  out[2 * NTOK + (size_t)t * 2 + 0] = (float)i1;
  out[2 * NTOK + (size_t)t * 2 + 1] = (float)i2;
}

extern "C" void kernel_launch(void* const* d_in, const int* in_sizes, int n_in,
                              void* d_out, int out_size, void* d_ws,
                              size_t ws_size, hipStream_t stream) {
  const float* x = (const float*)d_in[0];
  const float* W = (const float*)d_in[1];
  const float* b = (const float*)d_in[2];
  float* out = (float*)d_out;
  float* logits = (float*)d_ws;  // NTOK * NEXP fp32 = 512 KB

  // ws is re-poisoned to 0xAA before every launch; zero the accumulator.
  hipMemsetAsync(d_ws, 0, (size_t)NTOK * NEXP * sizeof(float), stream);

  dim3 grid1(NTOK / TPB, NDB);
  gate_logits_kernel<<<grid1, TPB, 0, stream>>>(x, W, logits);

  gate_topk_kernel<<<NTOK / 256, 256, 0, stream>>>(logits, b, out);
}